// Round 3
// baseline (421.771 us; speedup 1.0000x reference)
//
#include <hip/hip_runtime.h>

#define B_ 8
#define H_ 128
#define W_ 256
#define C_ 128
#define D_ 128
#define PS 136   // bf16 LDS row stride (272 B): 4-bank shift/row -> conflict-free b128
#define W1S 136  // w1b LDS stride
#define DS 10    // dmat stride (floats)

typedef __attribute__((ext_vector_type(4))) float f32x4;
typedef __attribute__((ext_vector_type(8))) short s16x8;
typedef __attribute__((ext_vector_type(4))) unsigned short u16x4;

__device__ __forceinline__ unsigned short f2bf(float f) {
    union { float f; unsigned u; } v; v.f = f;
    unsigned r = v.u + 0x7fffu + ((v.u >> 16) & 1u);   // RNE
    return (unsigned short)(r >> 16);
}
__device__ __forceinline__ float bf2f(unsigned short u) {
    union { unsigned u; float f; } v; v.u = ((unsigned)u) << 16; return v.f;
}
__device__ __forceinline__ float relu(float v) { return fmaxf(v, 0.f); }

// ---------------------------------------------------------------- K0
// Per row: stream x -> bf16 (xb global + xl LDS), conv1 via MFMA:
//   d[w][tap] = sum_c x[w][c]*w1[tap][c]   (M=256,N=16(9),K=128 GEMM)
//   c1x[w] = b1 + sum_tap d[w+tap-4][tap]
// Staging blocks build w2t (bf16 [d][c]), cs2 (colsum w2), s1 (rowsum w1).
__global__ __launch_bounds__(256) void k0_conv1(
    const float* __restrict__ x, const float* __restrict__ w1,
    const float* __restrict__ b1, const float* __restrict__ w2,
    float* __restrict__ c1x, float* __restrict__ s1,
    unsigned short* __restrict__ w2t, float* __restrict__ cs2,
    unsigned short* __restrict__ xb_out) {
    int bid = blockIdx.x, tid = threadIdx.x;
    if (bid >= B_ * H_) {                      // staging blocks
        int idx = (bid - B_ * H_) * 256 + tid; // 0..16383
        int d = idx & (D_ - 1), c = idx >> 7;
        w2t[d * C_ + c] = f2bf(w2[4 * C_ * D_ + c * D_ + d]);
        if (bid == B_ * H_) {
            if (tid < D_) {
                float s = 0.f;
                for (int cc = 0; cc < C_; ++cc) s += w2[4 * C_ * D_ + cc * D_ + tid];
                cs2[tid] = s;
            } else if (tid >= 128 && tid < 137) {
                int k = tid - 128;
                float s = 0.f;
                for (int c = 0; c < C_; ++c) s += w1[k * C_ + c];
                s1[k] = s;
            }
        }
        return;
    }
    __shared__ unsigned short xl[W_ * PS];     // 69632 B
    __shared__ unsigned short w1b[16 * W1S];   // 4352 B
    __shared__ float dmat[W_ * DS];            // 10240 B

    for (int t = tid; t < 16 * C_; t += 256) { // w1 -> bf16, taps 9..15 zeroed
        int k = t >> 7, c = t & 127;
        w1b[k * W1S + c] = (k < 9) ? f2bf(w1[k * C_ + c]) : (unsigned short)0;
    }
    const f32x4* xr4 = (const f32x4*)(x + (size_t)bid * (W_ * C_));
    u16x4* xb4 = xb_out ? (u16x4*)(xb_out + (size_t)bid * (W_ * C_)) : (u16x4*)0;
    for (int t = tid; t < (W_ * C_) / 4; t += 256) {
        f32x4 v = xr4[t];
        u16x4 o;
#pragma unroll
        for (int j = 0; j < 4; ++j) o[j] = f2bf(v[j]);
        if (xb4) xb4[t] = o;
        int w = t >> 5, c4 = t & 31;
        *(u16x4*)&xl[w * PS + c4 * 4] = o;
    }
    __syncthreads();

    int wv = tid >> 6, l = tid & 63, q = l >> 4, l15 = l & 15;
    s16x8 bfr[4];
#pragma unroll
    for (int kk = 0; kk < 4; ++kk)
        bfr[kk] = *(const s16x8*)&w1b[l15 * W1S + kk * 32 + q * 8];
#pragma unroll
    for (int mt = 0; mt < 4; ++mt) {
        int m0 = (wv * 4 + mt) * 16;
        f32x4 acc = (f32x4){0.f, 0.f, 0.f, 0.f};
#pragma unroll
        for (int kk = 0; kk < 4; ++kk) {
            s16x8 af = *(const s16x8*)&xl[(m0 + l15) * PS + kk * 32 + q * 8];
            acc = __builtin_amdgcn_mfma_f32_16x16x32_bf16(af, bfr[kk], acc, 0, 0, 0);
        }
        if (l15 < 10) {
#pragma unroll
            for (int r = 0; r < 4; ++r) dmat[(m0 + q * 4 + r) * DS + l15] = acc[r];
        }
    }
    __syncthreads();
    {   // c1x[w] = b1 + sum_k d[w+k-4][k]
        int w = tid;
        float s = b1[0];
#pragma unroll
        for (int k = 0; k < 9; ++k) {
            int wp = w + k - 4;
            if (wp >= 0 && wp < W_) s += dmat[wp * DS + k];
        }
        c1x[(size_t)bid * W_ + w] = s;
    }
}

// ---------------------------------------------------------------- K12 (fused passes 1-4)
// 512 threads: 8 waves, each owns a 64x64 (MxN) tile -> acc[4][4] = 64 AGPR.
__global__ __launch_bounds__(512, 4) void k12_fused(
    const float* __restrict__ x, const unsigned short* __restrict__ xb,
    const float* __restrict__ b2, const float* __restrict__ c1x_all,
    const float* __restrict__ s1, const unsigned short* __restrict__ w2t,
    const float* __restrict__ cs2, float* __restrict__ qout) {
    __shared__ unsigned short p_lds[W_ * PS];   // 69632 B
    __shared__ float sc[W_];                    // 1024 B
    int bid = blockIdx.x;            // row index b*H + i
    int b = bid >> 7, i = bid & 127;
    int tid = threadIdx.x;
    const float* c1 = c1x_all + (size_t)b * H_ * W_;

    int rowY;
    if (i == H_ - 1) rowY = H_ - 1;
    else if (i <= H_ - 3) rowY = (i - 1) & (H_ - 1);
    else rowY = H_ - 2;
    if (tid < W_) {   // phase 0: per-w scalar (verified rounds 1-2)
        int w = tid;
        float scv;
        if (i == H_ - 1) {
            scv = relu(c1[(H_ - 2) * W_ + w]);
        } else {
            int iu = (i <= H_ - 3) ? i : (H_ - 1);
            float cu = c1[iu * W_ + w];
            if (iu >= 1) {
                const float* tp = c1 + (iu - 1) * W_;
#pragma unroll
                for (int k = 0; k < 9; ++k) {
                    int wk = w + k - 4;
                    if (wk >= 0 && wk < W_) cu += relu(tp[wk]) * s1[k];
                }
            }
            float tY = (rowY >= 1) ? relu(c1[(rowY - 1) * W_ + w]) : 0.f;
            scv = tY + relu(cu);
        }
        sc[w] = scv;
    }
    __syncthreads();

    const float* zrow = x + ((size_t)b * H_ + rowY) * (W_ * C_);
    const unsigned short* zb = xb ? xb + ((size_t)b * H_ + rowY) * (W_ * C_) : (const unsigned short*)0;
    float* qrow = qout + (size_t)bid * (W_ * C_);

    if (tid < C_) {                  // p[0] = z[0] = x[0] + sc[0]
        float z0 = (zb ? bf2f(zb[tid]) : zrow[tid]) + sc[0];
        p_lds[tid] = f2bf(z0);
    }

    int wv = tid >> 6, l = tid & 63, q = l >> 4, l15 = l & 15;
    int m0 = (wv & 3) * 64, n0 = (wv >> 2) * 64;
    float b2v[4], cs2v[4];
#pragma unroll
    for (int nt = 0; nt < 4; ++nt) {
        int c = n0 + nt * 16 + l15;
        b2v[nt] = b2[c]; cs2v[nt] = cs2[c];
    }

    f32x4 acc[4][4];
#pragma unroll
    for (int mt = 0; mt < 4; ++mt)
#pragma unroll
        for (int nt = 0; nt < 4; ++nt) acc[mt][nt] = (f32x4){0.f, 0.f, 0.f, 0.f};

    // ---- GEMM1: A = bf16(x row), sc folded as rank-1 in epilogue
#pragma unroll
    for (int kk = 0; kk < C_; kk += 32) {
        s16x8 af[4], bfr[4];
#pragma unroll
        for (int mt = 0; mt < 4; ++mt) {
            int w = m0 + mt * 16 + l15;
            if (zb) {
                af[mt] = *(const s16x8*)(zb + w * C_ + kk + q * 8);
            } else {
                const float* ap = zrow + w * C_ + kk + q * 8;
                f32x4 f0 = *(const f32x4*)ap;
                f32x4 f1 = *(const f32x4*)(ap + 4);
                s16x8 t;
#pragma unroll
                for (int j = 0; j < 4; ++j) t[j] = (short)f2bf(f0[j]);
#pragma unroll
                for (int j = 0; j < 4; ++j) t[4 + j] = (short)f2bf(f1[j]);
                af[mt] = t;
            }
        }
#pragma unroll
        for (int nt = 0; nt < 4; ++nt)
            bfr[nt] = *(const s16x8*)(w2t + (n0 + nt * 16 + l15) * C_ + kk + q * 8);
#pragma unroll
        for (int mt = 0; mt < 4; ++mt)
#pragma unroll
            for (int nt = 0; nt < 4; ++nt)
                acc[mt][nt] = __builtin_amdgcn_mfma_f32_16x16x32_bf16(af[mt], bfr[nt], acc[mt][nt], 0, 0, 0);
    }
    // ---- epilogue 1: p[w+1] = x[w+1] + sc[w+1] + v[w]  -> LDS bf16
#pragma unroll
    for (int nt = 0; nt < 4; ++nt) {
        int c = n0 + nt * 16 + l15;
#pragma unroll
        for (int mt = 0; mt < 4; ++mt) {
#pragma unroll
            for (int r = 0; r < 4; ++r) {
                int w = m0 + mt * 16 + q * 4 + r;
                float v = relu(acc[mt][nt][r] + sc[w] * cs2v[nt] + b2v[nt]);
                if (w < W_ - 1) {
                    float zv = zb ? bf2f(zb[(w + 1) * C_ + c]) : zrow[(w + 1) * C_ + c];
                    float p = zv + sc[w + 1] + v;
                    p_lds[(w + 1) * PS + c] = f2bf(p);
                    if (w == W_ - 2) qrow[(W_ - 1) * C_ + c] = p;   // q[W-1] = p[W-1], exact fp32
                }
            }
        }
    }
    __syncthreads();

    // ---- GEMM2: A = p (bf16, LDS)
#pragma unroll
    for (int mt = 0; mt < 4; ++mt)
#pragma unroll
        for (int nt = 0; nt < 4; ++nt) acc[mt][nt] = (f32x4){0.f, 0.f, 0.f, 0.f};
#pragma unroll
    for (int kk = 0; kk < C_; kk += 32) {
        s16x8 af[4], bfr[4];
#pragma unroll
        for (int mt = 0; mt < 4; ++mt) {
            int w = m0 + mt * 16 + l15;
            af[mt] = *(const s16x8*)(&p_lds[w * PS + kk + q * 8]);
        }
#pragma unroll
        for (int nt = 0; nt < 4; ++nt)
            bfr[nt] = *(const s16x8*)(w2t + (n0 + nt * 16 + l15) * C_ + kk + q * 8);
#pragma unroll
        for (int mt = 0; mt < 4; ++mt)
#pragma unroll
            for (int nt = 0; nt < 4; ++nt)
                acc[mt][nt] = __builtin_amdgcn_mfma_f32_16x16x32_bf16(af[mt], bfr[nt], acc[mt][nt], 0, 0, 0);
    }
    // ---- epilogue 2: q stores
#pragma unroll
    for (int nt = 0; nt < 4; ++nt) {
        int c = n0 + nt * 16 + l15;
#pragma unroll
        for (int mt = 0; mt < 4; ++mt) {
#pragma unroll
            for (int r = 0; r < 4; ++r) {
                int w = m0 + mt * 16 + q * 4 + r;
                if (w == W_ - 2) continue;       // r[W-2] unused; q[W-1] already stored
                float rr = relu(acc[mt][nt][r] + b2v[nt]);
                float pv = bf2f(p_lds[((w - 1) & (W_ - 1)) * PS + c]);
                int wd = (w <= W_ - 3) ? w : (W_ - 2);   // w==W-1 -> q[W-2] = r[W-1] + p[W-2]
                qrow[wd * C_ + c] = rr + pv;
            }
        }
    }
}

extern "C" void kernel_launch(void* const* d_in, const int* in_sizes, int n_in,
                              void* d_out, int out_size, void* d_ws, size_t ws_size,
                              hipStream_t stream) {
    const float* x  = (const float*)d_in[0];
    const float* w1 = (const float*)d_in[1];
    const float* b1 = (const float*)d_in[2];
    const float* w2 = (const float*)d_in[3];
    const float* b2 = (const float*)d_in[4];
    float* out = (float*)d_out;

    float* wsf = (float*)d_ws;
    // ws layout (floats): c1x[262144] | s1[16] | w2t[8192] | cs2[128] | xb[16777216]
    float* c1x = wsf;
    float* s1  = wsf + 262144;
    unsigned short* w2t = (unsigned short*)(wsf + 262160);
    float* cs2 = wsf + 270352;
    size_t need_bytes = ((size_t)270480 + 16777216) * 4;   // xb = 33554432 shorts
    unsigned short* xb = (ws_size >= need_bytes) ? (unsigned short*)(wsf + 270480)
                                                 : (unsigned short*)0;

    k0_conv1<<<B_ * H_ + (C_ * D_) / 256, 256, 0, stream>>>(x, w1, b1, w2, c1x, s1, w2t, cs2, xb);
    k12_fused<<<B_ * H_, 512, 0, stream>>>(x, xb, b2, c1x, s1, w2t, cs2, out);
}